// Round 15
// baseline (19070.853 us; speedup 1.0000x reference)
//
#include <hip/hip_runtime.h>
#include <hip/hip_bf16.h>
#include <math.h>

#define NLAYERS 32
#define DM 1440
#define DI 2880
#define DSTATE 128
#define HD 64
#define NH 45
#define VOCABSZ 256
#define CHUNK 128
#define DXBC 3136
#define DPROJ 6061
#define BB 2
#define LL 2048
#define ROWS (BB*LL)
#define NCH (LL/CHUNK)
#define ZXS 6144          // padded zx row stride
#define STR 136           // LDS leading dim for [*][128] tiles
#define STR2 68           // LDS leading dim for [*][64] tiles

typedef __attribute__((ext_vector_type(8))) short bf16x8;
typedef __attribute__((ext_vector_type(4))) float f32x4;
typedef unsigned short us;

__device__ __forceinline__ float sigmoidf_(float x){ return 1.0f/(1.0f+__expf(-x)); }
__device__ __forceinline__ us f2b(float f){
  unsigned int u = __float_as_uint(f);
  return (us)((u + 0x7FFFu + ((u>>16)&1u)) >> 16);
}
__device__ __forceinline__ float b2f(us s){
  return __uint_as_float(((unsigned int)s)<<16);
}
__device__ __forceinline__ void split2(float v, us* ph, us* pl){
  us h = f2b(v);
  *ph = h;
  *pl = f2b(v - b2f(h));
}
__device__ __forceinline__ void gl2lds16(const us* g, us* l){
  __builtin_amdgcn_global_load_lds((const __attribute__((address_space(1))) unsigned int*)g,
                                   (__attribute__((address_space(3))) unsigned int*)l, 16, 0, 0);
}
#define MFMA(a,b,c) __builtin_amdgcn_mfma_f32_16x16x32_bf16(a,b,c,0,0,0)

// ---------------- embedding lookup (h tight [4096][1440]) ----------------
__global__ void k_embed(const int* __restrict__ tok, const float* __restrict__ emb, float* __restrict__ h){
  int idx = blockIdx.x*256 + threadIdx.x;
  if (idx >= ROWS*DM) return;
  int row = idx / DM, d = idx - row*DM;
  h[idx] = emb[tok[row]*DM + d];
}

// ---------------- split fp32 rows (tight) -> hi/lo bf16 (tight) ----------------
__global__ void k_split_rows(const float* __restrict__ src, us* __restrict__ dh,
                             us* __restrict__ dl, int ncols){
  size_t e = ((size_t)blockIdx.x*256 + threadIdx.x)*8;
  const float* s = src + e;
  bf16x8 oh, ol;
  #pragma unroll
  for (int j=0;j<8;j++){
    float v = s[j];
    us hh = f2b(v);
    ((us*)&oh)[j] = hh;
    ((us*)&ol)[j] = f2b(v - b2f(hh));
  }
  *(bf16x8*)(dh + e) = oh;
  *(bf16x8*)(dl + e) = ol;
}

// ---------------- standalone W[K][N] fp32 -> WT pair (prologue Win0 only) ----------------
__global__ void k_transcast_sp(const float* __restrict__ W, us* __restrict__ WTh,
                               us* __restrict__ WTl, int K, int N){
  __shared__ float t[32][65];
  int tid = threadIdx.x;
  int n0 = blockIdx.x*64, k0 = blockIdx.y*32;
  #pragma unroll
  for (int i=0;i<8;i++){
    int e = i*256 + tid;
    int r = e >> 6, cc = e & 63;
    int n = n0 + cc;
    t[r][cc] = (n < N) ? W[(size_t)(k0+r)*N + n] : 0.f;
  }
  __syncthreads();
  int nrow = tid >> 2, kseg = (tid & 3)*8;
  bf16x8 oh, ol;
  #pragma unroll
  for (int j=0;j<8;j++){
    float v = t[kseg+j][nrow];
    us hh = f2b(v);
    ((us*)&oh)[j] = hh;
    ((us*)&ol)[j] = f2b(v - b2f(hh));
  }
  *(bf16x8*)(WTh + (size_t)(n0+nrow)*K + k0 + kseg) = oh;
  *(bf16x8*)(WTl + (size_t)(n0+nrow)*K + k0 + kseg) = ol;
}

// ---------------- split-bf16 MFMA GEMM (R4-verified core) + fused transcast tail blocks ------
template<bool ACC, bool SPL>
__global__ __launch_bounds__(256) void k_gemm_sp(const us* __restrict__ Ah, const us* __restrict__ Al,
      const us* __restrict__ Bh, const us* __restrict__ Bl, float* __restrict__ C,
      int K, int ldc, int N, int nbx, us* __restrict__ Oh, us* __restrict__ Ol,
      int ngemm, const float* __restrict__ tcW, us* __restrict__ tcH, us* __restrict__ tcL,
      int tcK, int tcN, int tcNBX){
  __shared__ __align__(16) us smem[16384];   // 32 KB union
  int bid = blockIdx.x;
  int tid = threadIdx.x;
  if (bid >= ngemm){
    int t = bid - ngemm;
    int n0 = (t % tcNBX)*64, k0 = (t / tcNBX)*32;
    float* tt = (float*)smem;                // [32][65]
    #pragma unroll
    for (int i=0;i<8;i++){
      int e = i*256 + tid;
      int r = e >> 6, cc = e & 63;
      int n = n0 + cc;
      tt[r*65+cc] = (n < tcN) ? tcW[(size_t)(k0+r)*tcN + n] : 0.f;
    }
    __syncthreads();
    int nrow = tid >> 2, kseg = (tid & 3)*8;
    bf16x8 oh, ol;
    #pragma unroll
    for (int j=0;j<8;j++){
      float v = tt[(kseg+j)*65 + nrow];
      us hh = f2b(v);
      ((us*)&oh)[j] = hh;
      ((us*)&ol)[j] = f2b(v - b2f(hh));
    }
    *(bf16x8*)(tcH + (size_t)(n0+nrow)*tcK + k0 + kseg) = oh;
    *(bf16x8*)(tcL + (size_t)(n0+nrow)*tcK + k0 + kseg) = ol;
    return;
  }
  us* sAh = smem;        us* sAl = smem + 4096;
  us* sBh = smem + 8192; us* sBl = smem + 12288;
  int q = ngemm >> 3;
  int wg = (bid & 7)*q + (bid >> 3);     // XCD-contiguous chunk
  int grp = wg / (4*nbx);
  int rem = wg - grp*4*nbx;
  int by = grp*4 + (rem & 3);
  int bx = rem >> 2;
  int m0 = by*128, n0 = bx*128;
  int lane = tid & 63, wid = tid >> 6;
  int wr = wid >> 1, wc = wid & 1;
  int r4 = lane >> 2, c4 = (lane & 3)*8;
  int fr = lane & 15, fk = (lane >> 4)*8;
  f32x4 acc[4][4];
  #pragma unroll
  for (int i=0;i<4;i++)
    #pragma unroll
    for (int j=0;j<4;j++) acc[i][j] = (f32x4){0.f,0.f,0.f,0.f};
  for (int kt = 0; kt < K; kt += 32){
    __syncthreads();
    size_t ra0 = (size_t)(m0 + wid*16     + r4)*K + kt + c4;
    size_t ra1 = (size_t)(m0 + (wid+4)*16 + r4)*K + kt + c4;
    size_t rb0 = (size_t)(n0 + wid*16     + r4)*K + kt + c4;
    size_t rb1 = (size_t)(n0 + (wid+4)*16 + r4)*K + kt + c4;
    gl2lds16(Ah + ra0, sAh + wid*512);
    gl2lds16(Ah + ra1, sAh + (wid+4)*512);
    gl2lds16(Al + ra0, sAl + wid*512);
    gl2lds16(Al + ra1, sAl + (wid+4)*512);
    gl2lds16(Bh + rb0, sBh + wid*512);
    gl2lds16(Bh + rb1, sBh + (wid+4)*512);
    gl2lds16(Bl + rb0, sBl + wid*512);
    gl2lds16(Bl + rb1, sBl + (wid+4)*512);
    __syncthreads();
    bf16x8 ah[4], al[4], bh[4], bl[4];
    #pragma unroll
    for (int i=0;i<4;i++){
      int ro = (wr*64 + i*16 + fr)*32 + fk;
      int co = (wc*64 + i*16 + fr)*32 + fk;
      ah[i] = *(const bf16x8*)(sAh + ro);
      al[i] = *(const bf16x8*)(sAl + ro);
      bh[i] = *(const bf16x8*)(sBh + co);
      bl[i] = *(const bf16x8*)(sBl + co);
    }
    #pragma unroll
    for (int i=0;i<4;i++)
      #pragma unroll
      for (int j=0;j<4;j++){
        acc[i][j] = MFMA(ah[i], bh[j], acc[i][j]);
        acc[i][j] = MFMA(ah[i], bl[j], acc[i][j]);
        acc[i][j] = MFMA(al[i], bh[j], acc[i][j]);
      }
  }
  int orow = (lane>>4)*4, ocol = lane & 15;
  #pragma unroll
  for (int i=0;i<4;i++)
    #pragma unroll
    for (int j=0;j<4;j++)
      #pragma unroll
      for (int r=0;r<4;r++){
        int col = n0 + wc*64 + j*16 + ocol;
        if (col < N){
          size_t off = (size_t)(m0 + wr*64 + i*16 + orow + r)*ldc + col;
          float v = acc[i][j][r] + (ACC ? C[off] : 0.f);
          C[off] = v;
          if (SPL) split2(v, &Oh[off], &Ol[off]);
        }
      }
}

// ---------------- causal depthwise conv(4)+SiLU (16-l chunks) + fused dt softplus ----------------
__global__ __launch_bounds__(256) void k_conv2(const float* __restrict__ zx, const float* __restrict__ cw,
                        const float* __restrict__ cb, us* __restrict__ xbh, us* __restrict__ xbl,
                        const float* __restrict__ dtb_in, float* __restrict__ dtb){
  int ch = blockIdx.x*256 + threadIdx.x;
  int l0 = blockIdx.y * 16;
  int b = blockIdx.z;
  if (ch < DXBC){
    float w0 = cw[ch*4+0], w1 = cw[ch*4+1], w2 = cw[ch*4+2], w3 = cw[ch*4+3];
    float bias = cb[ch];
    float x0=0.f, x1=0.f, x2=0.f;
    if (l0-3 >= 0) x0 = zx[(size_t)(b*LL + l0-3)*ZXS + DI + ch];
    if (l0-2 >= 0) x1 = zx[(size_t)(b*LL + l0-2)*ZXS + DI + ch];
    if (l0-1 >= 0) x2 = zx[(size_t)(b*LL + l0-1)*ZXS + DI + ch];
    #pragma unroll 4
    for (int l = l0; l < l0+16; ++l){
      float x3 = zx[(size_t)(b*LL + l)*ZXS + DI + ch];
      float s = bias + w0*x0 + w1*x1 + w2*x2 + w3*x3;
      float v = s * sigmoidf_(s);
      size_t off = (size_t)(b*LL + l)*DXBC + ch;
      split2(v, &xbh[off], &xbl[off]);
      x0 = x1; x1 = x2; x2 = x3;
    }
  } else if (ch < DXBC + NH){
    int hh = ch - DXBC;
    float bias = dtb_in[hh];
    #pragma unroll 4
    for (int l = l0; l < l0+16; ++l){
      size_t row = (size_t)(b*LL + l);
      float v = zx[row*ZXS + (DI+DXBC) + hh] + bias;
      dtb[row*NH + hh] = (v > 20.f) ? v : log1pf(__expf(v));
    }
  }
}

// ---------------- SSD A+Sraw merged: hh<NH -> chunk states; hh==NH -> S_raw = C@B^T ----------
// Both branches use the same 4x8704-us LDS union (70 KB -> 2 blocks/CU).
__global__ __launch_bounds__(256) void k_ssd_sst(const us* __restrict__ xbh, const us* __restrict__ xbl,
    const float* __restrict__ dtb, const float* __restrict__ Alog,
    float* __restrict__ acs, us* __restrict__ cst_h, us* __restrict__ cst_l,
    float* __restrict__ Sraw){
  __shared__ __align__(16) us sm0[64*STR], sm1[64*STR], sm2[64*STR], sm3[64*STR];
  __shared__ float sAcs[128];
  __shared__ float sDt[128];
  int tid = threadIdx.x;
  int hh = blockIdx.x, c = blockIdx.y, b = blockIdx.z;
  int t0 = b*LL + c*CHUNK;
  int lane = tid & 63, wid = tid >> 6;
  int fr = lane & 15, fk = (lane>>4)*8;
  int orow = (lane>>4)*4;

  if (hh == NH){
    // ---- S_raw branch: S = C @ B^T via n-halved K-split (same accumulation order as R12) ----
    us* sCh = sm0; us* sCl = sm1; us* sB2h = sm2; us* sB2l = sm3;   // [128 l][64 nn] STR2
    int wbase = wid*32;
    f32x4 accS[2][8];
    #pragma unroll
    for (int m=0;m<2;m++)
      #pragma unroll
      for (int j=0;j<8;j++) accS[m][j] = (f32x4){0.f,0.f,0.f,0.f};
    #pragma unroll
    for (int nh=0; nh<2; ++nh){
      __syncthreads();
      #pragma unroll 8
      for (int i=0;i<32;i++){
        int e = i*256 + tid;             // 8192 = 128 l x 64 nn (coalesced along nn)
        int l = e >> 6, nn = e & 63;
        size_t oc = (size_t)(t0+l)*DXBC + DI + DSTATE + nh*64 + nn;
        size_t ob = (size_t)(t0+l)*DXBC + DI + nh*64 + nn;
        sCh[l*STR2+nn] = xbh[oc];  sCl[l*STR2+nn] = xbl[oc];
        sB2h[l*STR2+nn] = xbh[ob]; sB2l[l*STR2+nn] = xbl[ob];
      }
      __syncthreads();
      #pragma unroll
      for (int ks=0; ks<2; ++ks){
        int ko = ks*32 + fk;
        bf16x8 a0h = *(const bf16x8*)(sCh + (wbase+fr)*STR2 + ko);
        bf16x8 a0l = *(const bf16x8*)(sCl + (wbase+fr)*STR2 + ko);
        bf16x8 a1h = *(const bf16x8*)(sCh + (wbase+16+fr)*STR2 + ko);
        bf16x8 a1l = *(const bf16x8*)(sCl + (wbase+16+fr)*STR2 + ko);
        #pragma unroll
        for (int j=0;j<8;j++){
          bf16x8 bh = *(const bf16x8*)(sB2h + (j*16+fr)*STR2 + ko);
          bf16x8 bl = *(const bf16x8*)(sB2l + (j*16+fr)*STR2 + ko);
          accS[0][j] = MFMA(a0h, bh, accS[0][j]);
          accS[0][j] = MFMA(a0h, bl, accS[0][j]);
          accS[0][j] = MFMA(a0l, bh, accS[0][j]);
          accS[1][j] = MFMA(a1h, bh, accS[1][j]);
          accS[1][j] = MFMA(a1h, bl, accS[1][j]);
          accS[1][j] = MFMA(a1l, bh, accS[1][j]);
        }
      }
    }
    size_t sbase = ((size_t)(b*NCH + c))*16384;
    #pragma unroll
    for (int m=0;m<2;m++)
      #pragma unroll
      for (int j=0;j<8;j++)
        #pragma unroll
        for (int r=0;r<4;r++){
          int l = wbase + m*16 + orow + r;
          int s = j*16 + fr;
          Sraw[sbase + l*128 + s] = accS[m][j][r];
        }
    return;
  }

  // ---- state branch (R14-verified body) ----
  us* sBTh = sm0; us* sBTl = sm1;   // [n-half][l] STR
  us* sXTh = sm2; us* sXTl = sm3;   // [p][l] STR
  float A_h = -__expf(Alog[hh]);
  if (tid < 128){
    float d = dtb[(size_t)(t0+tid)*NH + hh];
    sDt[tid] = d;
    sAcs[tid] = d * A_h;
  }
  __syncthreads();
  if (tid < 64){
    float v = sAcs[tid], w = sAcs[64+tid];
    #pragma unroll
    for (int off=1; off<64; off<<=1){
      float tv = __shfl_up(v, off, 64);
      float tw = __shfl_up(w, off, 64);
      if (tid >= off){ v += tv; w += tw; }
    }
    float tot = __shfl(v, 63, 64);
    sAcs[tid] = v;
    sAcs[64+tid] = w + tot;
  }
  __syncthreads();
  if (tid < 128) acs[(size_t)(t0+tid)*NH + hh] = sAcs[tid];
  float alast = sAcs[127];
  // X^T stage, 8x8-tiled decode: bank-conflict-free writes, 16B-segmented reads
  #pragma unroll 8
  for (int i=0;i<32;i++){
    int idx = i*256 + tid;
    int j = idx & 7, g = (idx>>3) & 7, pm = (idx>>6) & 7, lm = idx>>9;
    int p = pm*8 + j, l = lm*8 + g;
    size_t off = (size_t)(t0+l)*DXBC + hh*HD + p;
    float v = (b2f(xbh[off]) + b2f(xbl[off])) * sDt[l] * __expf(alast - sAcs[l]);
    split2(v, &sXTh[p*STR+l], &sXTl[p*STR+l]);
  }
  f32x4 acc[8];
  #pragma unroll
  for (int j=0;j<8;j++) acc[j] = (f32x4){0.f,0.f,0.f,0.f};
  #pragma unroll
  for (int nh=0; nh<2; ++nh){
    __syncthreads();
    #pragma unroll 8
    for (int i=0;i<32;i++){
      int idx = i*256 + tid;
      int j = idx & 7, g = (idx>>3) & 7, nm = (idx>>6) & 7, lm = idx>>9;
      int n = nm*8 + j, l = lm*8 + g;
      size_t off = (size_t)(t0+l)*DXBC + DI + nh*64 + n;
      sBTh[n*STR+l] = xbh[off];
      sBTl[n*STR+l] = xbl[off];
    }
    __syncthreads();
    #pragma unroll
    for (int ks=0; ks<4; ks++){
      bf16x8 ah = *(const bf16x8*)(sXTh + (wid*16 + fr)*STR + ks*32 + fk);
      bf16x8 al = *(const bf16x8*)(sXTl + (wid*16 + fr)*STR + ks*32 + fk);
      #pragma unroll
      for (int j=0;j<4;j++){
        bf16x8 bh = *(const bf16x8*)(sBTh + (j*16 + fr)*STR + ks*32 + fk);
        bf16x8 bl = *(const bf16x8*)(sBTl + (j*16 + fr)*STR + ks*32 + fk);
        acc[nh*4+j] = MFMA(ah, bh, acc[nh*4+j]);
        acc[nh*4+j] = MFMA(ah, bl, acc[nh*4+j]);
        acc[nh*4+j] = MFMA(al, bh, acc[nh*4+j]);
      }
    }
  }
  size_t cbase = (((size_t)(b*NCH + c)*NH) + hh)*8192;
  #pragma unroll
  for (int jj=0;jj<8;jj++)
    #pragma unroll
    for (int r=0;r<4;r++){
      int p = wid*16 + orow + r;
      int n = (jj>>2)*64 + (jj&3)*16 + fr;
      split2(acc[jj][r], &cst_h[cbase + p*128 + n], &cst_l[cbase + p*128 + n]);
    }
}

// ---------------- SSD B: sequential inter-chunk prefix (pair in place) ----------------
__global__ __launch_bounds__(256) void k_ssd_scan2(const float* __restrict__ acs,
      us* __restrict__ cst_h, us* __restrict__ cst_l){
  int tid = threadIdx.x;
  int hh = blockIdx.x, b = blockIdx.y, z = blockIdx.z;
  int base_e = z*1024;
  float P[4];
  #pragma unroll
  for (int i=0;i<4;i++) P[i] = 0.f;
  for (int c=0;c<NCH;c++){
    size_t base = (((size_t)(b*NCH + c)*NH) + hh)*8192 + base_e;
    float dec = __expf(acs[(size_t)(b*LL + c*CHUNK + CHUNK-1)*NH + hh]);
    #pragma unroll
    for (int i=0;i<4;i++){
      size_t e = base + i*256 + tid;
      float tmp = b2f(cst_h[e]) + b2f(cst_l[e]);
      split2(P[i], &cst_h[e], &cst_l[e]);
      P[i] = dec*P[i] + tmp;
    }
  }
}

// ---------------- SSD C (512 thr, 1 barrier, direct-global C/P/S; conflict-free X stage) --------
__global__ __launch_bounds__(512) void k_ssd_y_sp(const us* __restrict__ xbh, const us* __restrict__ xbl,
    const float* __restrict__ dtb, const float* __restrict__ acs,
    const us* __restrict__ cst_h, const us* __restrict__ cst_l,
    const float* __restrict__ Sraw, float* __restrict__ Yf){
  __shared__ __align__(16) us sXh[64*STR], sXl[64*STR];   // [p][s] pair
  __shared__ float sAcs[128];
  __shared__ float sDt[128];
  int tid = threadIdx.x;
  int hh = blockIdx.x, c = blockIdx.y, b = blockIdx.z;
  int t0 = b*LL + c*CHUNK;
  if (tid < 128){
    sAcs[tid] = acs[(size_t)(t0+tid)*NH + hh];
    sDt[tid]  = dtb[(size_t)(t0+tid)*NH + hh];
  }
  #pragma unroll 8
  for (int i=0;i<16;i++){
    int idx = i*512 + tid;
    int j = idx & 7, g = (idx>>3) & 7, pm = (idx>>6) & 7, lm = idx>>9;
    int p = pm*8 + j, s = lm*8 + g;
    size_t off = (size_t)(t0+s)*DXBC + hh*HD + p;
    sXh[p*STR + s] = xbh[off];
    sXl[p*STR + s] = xbl[off];
  }
  __syncthreads();
  int lane = tid & 63, wid = tid >> 6;
  int wbase = wid*16;
  int fr = lane & 15, fk = (lane>>4)*8;
  int orow = (lane>>4)*4;
  int l = wbase + fr;
  float acs_l = sAcs[l];
  size_t cbase = (((size_t)(b*NCH + c)*NH) + hh)*8192;
  size_t sbase = ((size_t)(b*NCH + c))*16384;
  size_t crow  = (size_t)(t0+l)*DXBC + DI + DSTATE;

  f32x4 accU[4], accD[4];
  #pragma unroll
  for (int j=0;j<4;j++){
    accU[j] = (f32x4){0.f,0.f,0.f,0.f};
    accD[j] = (f32x4){0.f,0.f,0.f,0.f};
  }
  #pragma unroll
  for (int kk=0; kk<4; ++kk){
    int ko = kk*32 + fk;
    bf16x8 ch8 = *(const bf16x8*)(xbh + crow + ko);
    bf16x8 cl8 = *(const bf16x8*)(xbl + crow + ko);
    #pragma unroll
    for (int j=0;j<4;j++){
      int prow = j*16 + fr;
      bf16x8 ph = *(const bf16x8*)(cst_h + cbase + prow*128 + ko);
      bf16x8 pl = *(const bf16x8*)(cst_l + cbase + prow*128 + ko);
      accU[j] = MFMA(ch8, ph, accU[j]);
      accU[j] = MFMA(ch8, pl, accU[j]);
      accU[j] = MFMA(cl8, ph, accU[j]);
    }
  }
  #pragma unroll
  for (int kk=0; kk<4; ++kk){
    int sc = kk*32 + fk;
    const float* rp = Sraw + sbase + (size_t)l*128 + sc;
    bf16x8 ah, al;
    #pragma unroll
    for (int jj=0;jj<8;jj++){
      int s = sc + jj;
      float v = (s <= l) ? rp[jj]*__expf(acs_l - sAcs[s])*sDt[s] : 0.f;
      us h2 = f2b(v);
      ((us*)&ah)[jj] = h2;
      ((us*)&al)[jj] = f2b(v - b2f(h2));
    }
    #pragma unroll
    for (int j=0;j<4;j++){
      bf16x8 xh = *(const bf16x8*)(sXh + (j*16+fr)*STR + sc);
      bf16x8 xl = *(const bf16x8*)(sXl + (j*16+fr)*STR + sc);
      accD[j] = MFMA(ah, xh, accD[j]);
      accD[j] = MFMA(ah, xl, accD[j]);
      accD[j] = MFMA(al, xh, accD[j]);
    }
  }
  #pragma unroll
  for (int r=0;r<4;r++){
    int lo = wbase + orow + r;
    float ea = __expf(sAcs[lo]);
    #pragma unroll
    for (int j=0;j<4;j++)
      Yf[(size_t)(t0+lo)*DI + hh*HD + j*16 + fr] = accD[j][r] + ea*accU[j][r];
  }
}

// ---------------- gate + RMSNorm -> split bf16 pair ----------------
__global__ __launch_bounds__(256) void k_gatenorm(const float* __restrict__ Yf,
                           const us* __restrict__ xbh, const us* __restrict__ xbl,
                           const float* __restrict__ zx, const float* __restrict__ Dp_l,
                           const float* __restrict__ nw, us* __restrict__ yh, us* __restrict__ yl){
  __shared__ float red[4];
  __shared__ float stot;
  int row = blockIdx.x;
  int tid = threadIdx.x;
  float yv_[12];
  float ss = 0.f;
  #pragma unroll
  for (int i=0;i<12;i++){
    int d = tid + i*256;
    if (d < DI){
      size_t xo = (size_t)row*DXBC + d;
      float xv = b2f(xbh[xo]) + b2f(xbl[xo]);
      float yv = Yf[(size_t)row*DI + d] + xv * Dp_l[d >> 6];
      float zv = zx[(size_t)row*ZXS + d];
      yv *= zv * sigmoidf_(zv);
      yv_[i] = yv;
      ss += yv*yv;
    } else yv_[i] = 0.f;
  }
  #pragma unroll
  for (int off=32; off>0; off>>=1) ss += __shfl_down(ss, off, 64);
  int lane = tid & 63, wid = tid >> 6;
  if (lane == 0) red[wid] = ss;
  __syncthreads();
  if (tid == 0) stot = red[0]+red[1]+red[2]+red[3];
  __syncthreads();
  float rs = rsqrtf(stot / (float)DI + 1e-5f);
  #pragma unroll
  for (int i=0;i<12;i++){
    int d = tid + i*256;
    if (d < DI){
      float v = yv_[i] * rs * nw[d];
      split2(v, &yh[(size_t)row*DI + d], &yl[(size_t)row*DI + d]);
    }
  }
}

// ---------------- final RMSNorm -> split bf16 pair ----------------
__global__ __launch_bounds__(256) void k_finalnorm(const float* __restrict__ h, const float* __restrict__ fnw,
                            us* __restrict__ oh, us* __restrict__ ol){
  __shared__ float red[4];
  __shared__ float stot;
  int row = blockIdx.x;
  int tid = threadIdx.x;
  float v_[6];
  float ss = 0.f;
  #pragma unroll
  for (int i=0;i<6;i++){
    int d = tid + i*256;
    if (d < DM){ v_[i] = h[(size_t)row*DM + d]; ss += v_[i]*v_[i]; }
    else v_[i] = 0.f;
  }
  #pragma unroll
  for (int off=32; off>0; off>>=1) ss += __shfl_down(ss, off, 64);
  int lane = tid & 63, wid = tid >> 6;
  if (lane == 0) red[wid] = ss;
  __syncthreads();
  if (tid == 0) stot = red[0]+red[1]+red[2]+red[3];
  __syncthreads();
  float rs = rsqrtf(stot / (float)DM + 1e-5f);
  #pragma unroll
  for (int i=0;i<6;i++){
    int d = tid + i*256;
    if (d < DM){
      float v = v_[i] * rs * fnw[d];
      split2(v, &oh[(size_t)row*DM + d], &ol[(size_t)row*DM + d]);
    }
  }
}

extern "C" void kernel_launch(void* const* d_in, const int* in_sizes, int n_in,
                              void* d_out, int out_size, void* d_ws, size_t ws_size,
                              hipStream_t stream){
  const int*   tok   = (const int*)d_in[0];
  const float* emb   = (const float*)d_in[1];
  const float* Win   = (const float*)d_in[2];
  const float* convw = (const float*)d_in[3];
  const float* convb = (const float*)d_in[4];
  const float* dtbias= (const float*)d_in[5];
  const float* Alog  = (const float*)d_in[6];
  const float* Dp    = (const float*)d_in[7];
  const float* normw = (const float*)d_in[8];
  const float* Wout  = (const float*)d_in[9];
  const float* fnw   = (const float*)d_in[10];

  float* ws = (float*)d_ws;
  // layout (floats): 326.7 MB total
  float* h    = ws;                        // 4096x1440 fp32
  float* zx   = ws + 5898240;              // 4096x6144 fp32
  us*    xbh  = (us*)(ws + 31064064);      // 4096x3136 bf16 hi
  us*    xbl  = (us*)(ws + 37486592);      // 4096x3136 bf16 lo
  us*    hp_h = (us*)(ws + 31064064);      // h pair overlay (dead once conv writes xb)
  us*    hp_l = (us*)(ws + 34013184);
  float* dtb  = ws + 43909120;
  float* acs  = ws + 44093440;
  float* Yf   = ws + 44277760;             // 4096x2880 fp32
  us* cst_h   = (us*)(ws + 56074240);      // OVERLAID with ab pair (disjoint lifetimes)
  us* cst_l   = (us*)(ws + 61972480);
  us* ab_h    = (us*)(ws + 56074240);
  us* ab_l    = (us*)(ws + 61972480);
  float* Sraw = ws + 67870720;             // 32x128x128 fp32
  us* winh    = (us*)(ws + 68395008);      // Win pair [6144][1440]
  us* winl    = (us*)(ws + 72818688);
  us* wouth   = (us*)(ws + 77242368);      // Wout pair [1536][2880] (also emb pair for logits)
  us* woutl   = (us*)(ws + 79454208);

  k_embed<<<(ROWS*DM+255)/256, 256, 0, stream>>>(tok, emb, h);
  k_split_rows<<<2880, 256, 0, stream>>>(h, hp_h, hp_l, DM);
  k_transcast_sp<<<dim3(ZXS/64, DM/32), 256, 0, stream>>>(Win, winh, winl, DM, DPROJ);  // layer 0
  for (int lyr=0; lyr<NLAYERS; ++lyr){
    // GEMM1 (1536 blocks) + fused Wout[lyr] transcast tail (2160 blocks)
    k_gemm_sp<false,false><<<1536 + 2160, 256, 0, stream>>>(
        hp_h, hp_l, winh, winl, zx, DM, ZXS, ZXS, ZXS/128, nullptr, nullptr,
        1536, Wout + (size_t)lyr*DI*DM, wouth, woutl, DI, DM, 24);
    k_conv2<<<dim3(13, 128, BB), 256, 0, stream>>>(
        zx, convw + (size_t)lyr*DXBC*4, convb + (size_t)lyr*DXBC, xbh, xbl,
        dtbias + lyr*NH, dtb);
    // merged: hh<NH -> chunk states; hh==NH -> Sraw
    k_ssd_sst<<<dim3(NH+1, NCH, BB), 256, 0, stream>>>(xbh, xbl, dtb, Alog + lyr*NH, acs, cst_h, cst_l, Sraw);
    k_ssd_scan2<<<dim3(NH, BB, 8), 256, 0, stream>>>(acs, cst_h, cst_l);
    k_ssd_y_sp<<<dim3(NH, NCH, BB), 512, 0, stream>>>(xbh, xbl, dtb, acs, cst_h, cst_l, Sraw, Yf);
    k_gatenorm<<<ROWS, 256, 0, stream>>>(Yf, xbh, xbl, zx, Dp + lyr*NH, normw + (size_t)lyr*DI, ab_h, ab_l);
    // GEMM2 (384 blocks) + fused Win[lyr+1] transcast tail (4320 blocks, except last layer)
    if (lyr+1 < NLAYERS){
      k_gemm_sp<true,true><<<384 + 4320, 256, 0, stream>>>(
          ab_h, ab_l, wouth, woutl, h, DI, DM, DM, 1536/128, hp_h, hp_l,
          384, Win + (size_t)(lyr+1)*DM*DPROJ, winh, winl, DM, DPROJ, 96);
    } else {
      k_gemm_sp<true,true><<<384, 256, 0, stream>>>(
          ab_h, ab_l, wouth, woutl, h, DI, DM, DM, 1536/128, hp_h, hp_l,
          384, nullptr, nullptr, nullptr, 0, 0, 1);
    }
  }
  k_finalnorm<<<ROWS, 256, 0, stream>>>(h, fnw, ab_h, ab_l);
  k_split_rows<<<180, 256, 0, stream>>>(emb, wouth, woutl, DM);   // emb pair -> wout region
  k_gemm_sp<false,false><<<(VOCABSZ/128)*(ROWS/128), 256, 0, stream>>>(
      ab_h, ab_l, wouth, woutl, (float*)d_out, DM, VOCABSZ, VOCABSZ, VOCABSZ/128, nullptr, nullptr,
      (VOCABSZ/128)*(ROWS/128), nullptr, nullptr, nullptr, 0, 0, 1);
}

// Round 16
// 18876.784 us; speedup vs baseline: 1.0103x; 1.0103x over previous
//
#include <hip/hip_runtime.h>
#include <hip/hip_bf16.h>
#include <math.h>

#define NLAYERS 32
#define DM 1440
#define DI 2880
#define DSTATE 128
#define HD 64
#define NH 45
#define VOCABSZ 256
#define CHUNK 128
#define DXBC 3136
#define DPROJ 6061
#define BB 2
#define LL 2048
#define ROWS (BB*LL)
#define NCH (LL/CHUNK)
#define ZXS 6144          // padded zx row stride
#define STR 136           // LDS leading dim for [*][128] tiles

typedef __attribute__((ext_vector_type(8))) short bf16x8;
typedef __attribute__((ext_vector_type(4))) float f32x4;
typedef unsigned short us;

__device__ __forceinline__ float sigmoidf_(float x){ return 1.0f/(1.0f+__expf(-x)); }
__device__ __forceinline__ us f2b(float f){
  unsigned int u = __float_as_uint(f);
  return (us)((u + 0x7FFFu + ((u>>16)&1u)) >> 16);
}
__device__ __forceinline__ float b2f(us s){
  return __uint_as_float(((unsigned int)s)<<16);
}
__device__ __forceinline__ void split2(float v, us* ph, us* pl){
  us h = f2b(v);
  *ph = h;
  *pl = f2b(v - b2f(h));
}
__device__ __forceinline__ void gl2lds16(const us* g, us* l){
  __builtin_amdgcn_global_load_lds((const __attribute__((address_space(1))) unsigned int*)g,
                                   (__attribute__((address_space(3))) unsigned int*)l, 16, 0, 0);
}
#define MFMA(a,b,c) __builtin_amdgcn_mfma_f32_16x16x32_bf16(a,b,c,0,0,0)

// ---------------- embedding lookup (h tight [4096][1440]) ----------------
__global__ void k_embed(const int* __restrict__ tok, const float* __restrict__ emb, float* __restrict__ h){
  int idx = blockIdx.x*256 + threadIdx.x;
  if (idx >= ROWS*DM) return;
  int row = idx / DM, d = idx - row*DM;
  h[idx] = emb[tok[row]*DM + d];
}

// ---------------- split fp32 rows (tight) -> hi/lo bf16 (tight) ----------------
__global__ void k_split_rows(const float* __restrict__ src, us* __restrict__ dh,
                             us* __restrict__ dl, int ncols){
  size_t e = ((size_t)blockIdx.x*256 + threadIdx.x)*8;
  const float* s = src + e;
  bf16x8 oh, ol;
  #pragma unroll
  for (int j=0;j<8;j++){
    float v = s[j];
    us hh = f2b(v);
    ((us*)&oh)[j] = hh;
    ((us*)&ol)[j] = f2b(v - b2f(hh));
  }
  *(bf16x8*)(dh + e) = oh;
  *(bf16x8*)(dl + e) = ol;
}

// ---------------- standalone W[K][N] fp32 -> WT pair (prologue Win0 only) ----------------
__global__ void k_transcast_sp(const float* __restrict__ W, us* __restrict__ WTh,
                               us* __restrict__ WTl, int K, int N){
  __shared__ float t[32][65];
  int tid = threadIdx.x;
  int n0 = blockIdx.x*64, k0 = blockIdx.y*32;
  #pragma unroll
  for (int i=0;i<8;i++){
    int e = i*256 + tid;
    int r = e >> 6, cc = e & 63;
    int n = n0 + cc;
    t[r][cc] = (n < N) ? W[(size_t)(k0+r)*N + n] : 0.f;
  }
  __syncthreads();
  int nrow = tid >> 2, kseg = (tid & 3)*8;
  bf16x8 oh, ol;
  #pragma unroll
  for (int j=0;j<8;j++){
    float v = t[kseg+j][nrow];
    us hh = f2b(v);
    ((us*)&oh)[j] = hh;
    ((us*)&ol)[j] = f2b(v - b2f(hh));
  }
  *(bf16x8*)(WTh + (size_t)(n0+nrow)*K + k0 + kseg) = oh;
  *(bf16x8*)(WTl + (size_t)(n0+nrow)*K + k0 + kseg) = ol;
}

// ---------------- split-bf16 MFMA GEMM (R4-verified core) + fused transcast tail blocks ------
template<bool ACC, bool SPL>
__global__ __launch_bounds__(256) void k_gemm_sp(const us* __restrict__ Ah, const us* __restrict__ Al,
      const us* __restrict__ Bh, const us* __restrict__ Bl, float* __restrict__ C,
      int K, int ldc, int N, int nbx, us* __restrict__ Oh, us* __restrict__ Ol,
      int ngemm, const float* __restrict__ tcW, us* __restrict__ tcH, us* __restrict__ tcL,
      int tcK, int tcN, int tcNBX){
  __shared__ __align__(16) us smem[16384];   // 32 KB union
  int bid = blockIdx.x;
  int tid = threadIdx.x;
  if (bid >= ngemm){
    int t = bid - ngemm;
    int n0 = (t % tcNBX)*64, k0 = (t / tcNBX)*32;
    float* tt = (float*)smem;                // [32][65]
    #pragma unroll
    for (int i=0;i<8;i++){
      int e = i*256 + tid;
      int r = e >> 6, cc = e & 63;
      int n = n0 + cc;
      tt[r*65+cc] = (n < tcN) ? tcW[(size_t)(k0+r)*tcN + n] : 0.f;
    }
    __syncthreads();
    int nrow = tid >> 2, kseg = (tid & 3)*8;
    bf16x8 oh, ol;
    #pragma unroll
    for (int j=0;j<8;j++){
      float v = tt[(kseg+j)*65 + nrow];
      us hh = f2b(v);
      ((us*)&oh)[j] = hh;
      ((us*)&ol)[j] = f2b(v - b2f(hh));
    }
    *(bf16x8*)(tcH + (size_t)(n0+nrow)*tcK + k0 + kseg) = oh;
    *(bf16x8*)(tcL + (size_t)(n0+nrow)*tcK + k0 + kseg) = ol;
    return;
  }
  us* sAh = smem;        us* sAl = smem + 4096;
  us* sBh = smem + 8192; us* sBl = smem + 12288;
  int q = ngemm >> 3;
  int wg = (bid & 7)*q + (bid >> 3);     // XCD-contiguous chunk
  int grp = wg / (4*nbx);
  int rem = wg - grp*4*nbx;
  int by = grp*4 + (rem & 3);
  int bx = rem >> 2;
  int m0 = by*128, n0 = bx*128;
  int lane = tid & 63, wid = tid >> 6;
  int wr = wid >> 1, wc = wid & 1;
  int r4 = lane >> 2, c4 = (lane & 3)*8;
  int fr = lane & 15, fk = (lane >> 4)*8;
  f32x4 acc[4][4];
  #pragma unroll
  for (int i=0;i<4;i++)
    #pragma unroll
    for (int j=0;j<4;j++) acc[i][j] = (f32x4){0.f,0.f,0.f,0.f};
  for (int kt = 0; kt < K; kt += 32){
    __syncthreads();
    size_t ra0 = (size_t)(m0 + wid*16     + r4)*K + kt + c4;
    size_t ra1 = (size_t)(m0 + (wid+4)*16 + r4)*K + kt + c4;
    size_t rb0 = (size_t)(n0 + wid*16     + r4)*K + kt + c4;
    size_t rb1 = (size_t)(n0 + (wid+4)*16 + r4)*K + kt + c4;
    gl2lds16(Ah + ra0, sAh + wid*512);
    gl2lds16(Ah + ra1, sAh + (wid+4)*512);
    gl2lds16(Al + ra0, sAl + wid*512);
    gl2lds16(Al + ra1, sAl + (wid+4)*512);
    gl2lds16(Bh + rb0, sBh + wid*512);
    gl2lds16(Bh + rb1, sBh + (wid+4)*512);
    gl2lds16(Bl + rb0, sBl + wid*512);
    gl2lds16(Bl + rb1, sBl + (wid+4)*512);
    __syncthreads();
    bf16x8 ah[4], al[4], bh[4], bl[4];
    #pragma unroll
    for (int i=0;i<4;i++){
      int ro = (wr*64 + i*16 + fr)*32 + fk;
      int co = (wc*64 + i*16 + fr)*32 + fk;
      ah[i] = *(const bf16x8*)(sAh + ro);
      al[i] = *(const bf16x8*)(sAl + ro);
      bh[i] = *(const bf16x8*)(sBh + co);
      bl[i] = *(const bf16x8*)(sBl + co);
    }
    #pragma unroll
    for (int i=0;i<4;i++)
      #pragma unroll
      for (int j=0;j<4;j++){
        acc[i][j] = MFMA(ah[i], bh[j], acc[i][j]);
        acc[i][j] = MFMA(ah[i], bl[j], acc[i][j]);
        acc[i][j] = MFMA(al[i], bh[j], acc[i][j]);
      }
  }
  int orow = (lane>>4)*4, ocol = lane & 15;
  #pragma unroll
  for (int i=0;i<4;i++)
    #pragma unroll
    for (int j=0;j<4;j++)
      #pragma unroll
      for (int r=0;r<4;r++){
        int col = n0 + wc*64 + j*16 + ocol;
        if (col < N){
          size_t off = (size_t)(m0 + wr*64 + i*16 + orow + r)*ldc + col;
          float v = acc[i][j][r] + (ACC ? C[off] : 0.f);
          C[off] = v;
          if (SPL) split2(v, &Oh[off], &Ol[off]);
        }
      }
}

// ---------------- causal depthwise conv(4)+SiLU (16-l chunks) + fused dt softplus ----------------
__global__ __launch_bounds__(256) void k_conv2(const float* __restrict__ zx, const float* __restrict__ cw,
                        const float* __restrict__ cb, us* __restrict__ xbh, us* __restrict__ xbl,
                        const float* __restrict__ dtb_in, float* __restrict__ dtb){
  int ch = blockIdx.x*256 + threadIdx.x;
  int l0 = blockIdx.y * 16;
  int b = blockIdx.z;
  if (ch < DXBC){
    float w0 = cw[ch*4+0], w1 = cw[ch*4+1], w2 = cw[ch*4+2], w3 = cw[ch*4+3];
    float bias = cb[ch];
    float x0=0.f, x1=0.f, x2=0.f;
    if (l0-3 >= 0) x0 = zx[(size_t)(b*LL + l0-3)*ZXS + DI + ch];
    if (l0-2 >= 0) x1 = zx[(size_t)(b*LL + l0-2)*ZXS + DI + ch];
    if (l0-1 >= 0) x2 = zx[(size_t)(b*LL + l0-1)*ZXS + DI + ch];
    #pragma unroll 4
    for (int l = l0; l < l0+16; ++l){
      float x3 = zx[(size_t)(b*LL + l)*ZXS + DI + ch];
      float s = bias + w0*x0 + w1*x1 + w2*x2 + w3*x3;
      float v = s * sigmoidf_(s);
      size_t off = (size_t)(b*LL + l)*DXBC + ch;
      split2(v, &xbh[off], &xbl[off]);
      x0 = x1; x1 = x2; x2 = x3;
    }
  } else if (ch < DXBC + NH){
    int hh = ch - DXBC;
    float bias = dtb_in[hh];
    #pragma unroll 4
    for (int l = l0; l < l0+16; ++l){
      size_t row = (size_t)(b*LL + l);
      float v = zx[row*ZXS + (DI+DXBC) + hh] + bias;
      dtb[row*NH + hh] = (v > 20.f) ? v : log1pf(__expf(v));
    }
  }
}

// ---------------- S_raw = C @ B^T per (chunk,batch) — head-independent (R12-proven) ----------------
__global__ __launch_bounds__(256) void k_sraw(const us* __restrict__ xbh, const us* __restrict__ xbl,
                                              float* __restrict__ Sraw){
  __shared__ __align__(16) us sCh[128*STR], sCl[128*STR], sB2h[128*STR], sB2l[128*STR];
  int tid = threadIdx.x;
  int c = blockIdx.x, b = blockIdx.y;
  int t0 = b*LL + c*CHUNK;
  #pragma unroll
  for (int i=0;i<8;i++){
    int e = i*256 + tid;
    int l = e >> 4, seg = (e & 15)*8;
    size_t oc = (size_t)(t0+l)*DXBC + DI + DSTATE + seg;
    size_t ob = (size_t)(t0+l)*DXBC + DI + seg;
    *(bf16x8*)(sCh + l*STR + seg) = *(const bf16x8*)(xbh + oc);
    *(bf16x8*)(sCl + l*STR + seg) = *(const bf16x8*)(xbl + oc);
    *(bf16x8*)(sB2h + l*STR + seg) = *(const bf16x8*)(xbh + ob);
    *(bf16x8*)(sB2l + l*STR + seg) = *(const bf16x8*)(xbl + ob);
  }
  __syncthreads();
  int lane = tid & 63, wid = tid >> 6;
  int wbase = wid*32;
  int fr = lane & 15, fk = (lane>>4)*8;
  int orow = (lane>>4)*4;
  f32x4 accS[2][8];
  #pragma unroll
  for (int m=0;m<2;m++)
    #pragma unroll
    for (int j=0;j<8;j++) accS[m][j] = (f32x4){0.f,0.f,0.f,0.f};
  #pragma unroll
  for (int ks=0; ks<4; ++ks){
    int ko = ks*32 + fk;
    bf16x8 a0h = *(const bf16x8*)(sCh + (wbase+fr)*STR + ko);
    bf16x8 a0l = *(const bf16x8*)(sCl + (wbase+fr)*STR + ko);
    bf16x8 a1h = *(const bf16x8*)(sCh + (wbase+16+fr)*STR + ko);
    bf16x8 a1l = *(const bf16x8*)(sCl + (wbase+16+fr)*STR + ko);
    #pragma unroll
    for (int j=0;j<8;j++){
      bf16x8 bh = *(const bf16x8*)(sB2h + (j*16+fr)*STR + ko);
      bf16x8 bl = *(const bf16x8*)(sB2l + (j*16+fr)*STR + ko);
      accS[0][j] = MFMA(a0h, bh, accS[0][j]);
      accS[0][j] = MFMA(a0h, bl, accS[0][j]);
      accS[0][j] = MFMA(a0l, bh, accS[0][j]);
      accS[1][j] = MFMA(a1h, bh, accS[1][j]);
      accS[1][j] = MFMA(a1h, bl, accS[1][j]);
      accS[1][j] = MFMA(a1l, bh, accS[1][j]);
    }
  }
  size_t sbase = ((size_t)(b*NCH + c))*16384;
  #pragma unroll
  for (int m=0;m<2;m++)
    #pragma unroll
    for (int j=0;j<8;j++)
      #pragma unroll
      for (int r=0;r<4;r++){
        int l = wbase + m*16 + orow + r;
        int s = j*16 + fr;
        Sraw[sbase + l*128 + s] = accS[m][j][r];
      }
}

// ---------------- SSD A (R14-verified; conflict-free 8x8 staging decode) ----------------
__global__ __launch_bounds__(256) void k_ssd_state_sp(const us* __restrict__ xbh, const us* __restrict__ xbl,
    const float* __restrict__ dtb, const float* __restrict__ Alog,
    float* __restrict__ acs, us* __restrict__ cst_h, us* __restrict__ cst_l){
  __shared__ __align__(16) us sBTh[64*STR], sBTl[64*STR];   // [n-half][l]
  __shared__ __align__(16) us sXTh[64*STR], sXTl[64*STR];   // [p][l]
  __shared__ float sAcs[128];
  __shared__ float sDt[128];
  int tid = threadIdx.x;
  int hh = blockIdx.x, c = blockIdx.y, b = blockIdx.z;
  int t0 = b*LL + c*CHUNK;
  float A_h = -__expf(Alog[hh]);
  if (tid < 128){
    float d = dtb[(size_t)(t0+tid)*NH + hh];
    sDt[tid] = d;
    sAcs[tid] = d * A_h;
  }
  __syncthreads();
  if (tid < 64){
    float v = sAcs[tid], w = sAcs[64+tid];
    #pragma unroll
    for (int off=1; off<64; off<<=1){
      float tv = __shfl_up(v, off, 64);
      float tw = __shfl_up(w, off, 64);
      if (tid >= off){ v += tv; w += tw; }
    }
    float tot = __shfl(v, 63, 64);
    sAcs[tid] = v;
    sAcs[64+tid] = w + tot;
  }
  __syncthreads();
  if (tid < 128) acs[(size_t)(t0+tid)*NH + hh] = sAcs[tid];
  float alast = sAcs[127];
  #pragma unroll 8
  for (int i=0;i<32;i++){
    int idx = i*256 + tid;
    int j = idx & 7, g = (idx>>3) & 7, pm = (idx>>6) & 7, lm = idx>>9;
    int p = pm*8 + j, l = lm*8 + g;
    size_t off = (size_t)(t0+l)*DXBC + hh*HD + p;
    float v = (b2f(xbh[off]) + b2f(xbl[off])) * sDt[l] * __expf(alast - sAcs[l]);
    split2(v, &sXTh[p*STR+l], &sXTl[p*STR+l]);
  }
  int lane = tid & 63, wid = tid >> 6;
  int fr = lane & 15, fk = (lane>>4)*8;
  f32x4 acc[8];
  #pragma unroll
  for (int j=0;j<8;j++) acc[j] = (f32x4){0.f,0.f,0.f,0.f};
  #pragma unroll
  for (int nh=0; nh<2; ++nh){
    __syncthreads();
    #pragma unroll 8
    for (int i=0;i<32;i++){
      int idx = i*256 + tid;
      int j = idx & 7, g = (idx>>3) & 7, nm = (idx>>6) & 7, lm = idx>>9;
      int n = nm*8 + j, l = lm*8 + g;
      size_t off = (size_t)(t0+l)*DXBC + DI + nh*64 + n;
      sBTh[n*STR+l] = xbh[off];
      sBTl[n*STR+l] = xbl[off];
    }
    __syncthreads();
    #pragma unroll
    for (int ks=0; ks<4; ks++){
      bf16x8 ah = *(const bf16x8*)(sXTh + (wid*16 + fr)*STR + ks*32 + fk);
      bf16x8 al = *(const bf16x8*)(sXTl + (wid*16 + fr)*STR + ks*32 + fk);
      #pragma unroll
      for (int j=0;j<4;j++){
        bf16x8 bh = *(const bf16x8*)(sBTh + (j*16 + fr)*STR + ks*32 + fk);
        bf16x8 bl = *(const bf16x8*)(sBTl + (j*16 + fr)*STR + ks*32 + fk);
        acc[nh*4+j] = MFMA(ah, bh, acc[nh*4+j]);
        acc[nh*4+j] = MFMA(ah, bl, acc[nh*4+j]);
        acc[nh*4+j] = MFMA(al, bh, acc[nh*4+j]);
      }
    }
  }
  size_t cbase = (((size_t)(b*NCH + c)*NH) + hh)*8192;
  int orow = (lane>>4)*4;
  #pragma unroll
  for (int jj=0;jj<8;jj++)
    #pragma unroll
    for (int r=0;r<4;r++){
      int p = wid*16 + orow + r;
      int n = (jj>>2)*64 + (jj&3)*16 + fr;
      split2(acc[jj][r], &cst_h[cbase + p*128 + n], &cst_l[cbase + p*128 + n]);
    }
}

// ---------------- SSD B: sequential inter-chunk prefix (pair in place) ----------------
__global__ __launch_bounds__(256) void k_ssd_scan2(const float* __restrict__ acs,
      us* __restrict__ cst_h, us* __restrict__ cst_l){
  int tid = threadIdx.x;
  int hh = blockIdx.x, b = blockIdx.y, z = blockIdx.z;
  int base_e = z*1024;
  float P[4];
  #pragma unroll
  for (int i=0;i<4;i++) P[i] = 0.f;
  for (int c=0;c<NCH;c++){
    size_t base = (((size_t)(b*NCH + c)*NH) + hh)*8192 + base_e;
    float dec = __expf(acs[(size_t)(b*LL + c*CHUNK + CHUNK-1)*NH + hh]);
    #pragma unroll
    for (int i=0;i<4;i++){
      size_t e = base + i*256 + tid;
      float tmp = b2f(cst_h[e]) + b2f(cst_l[e]);
      split2(P[i], &cst_h[e], &cst_l[e]);
      P[i] = dec*P[i] + tmp;
    }
  }
}

// ---------------- SSD C (512 thr, 1 barrier, direct-global C/P/S; conflict-free X stage) --------
__global__ __launch_bounds__(512) void k_ssd_y_sp(const us* __restrict__ xbh, const us* __restrict__ xbl,
    const float* __restrict__ dtb, const float* __restrict__ acs,
    const us* __restrict__ cst_h, const us* __restrict__ cst_l,
    const float* __restrict__ Sraw, float* __restrict__ Yf){
  __shared__ __align__(16) us sXh[64*STR], sXl[64*STR];   // [p][s] pair
  __shared__ float sAcs[128];
  __shared__ float sDt[128];
  int tid = threadIdx.x;
  int hh = blockIdx.x, c = blockIdx.y, b = blockIdx.z;
  int t0 = b*LL + c*CHUNK;
  if (tid < 128){
    sAcs[tid] = acs[(size_t)(t0+tid)*NH + hh];
    sDt[tid]  = dtb[(size_t)(t0+tid)*NH + hh];
  }
  #pragma unroll 8
  for (int i=0;i<16;i++){
    int idx = i*512 + tid;
    int j = idx & 7, g = (idx>>3) & 7, pm = (idx>>6) & 7, lm = idx>>9;
    int p = pm*8 + j, s = lm*8 + g;
    size_t off = (size_t)(t0+s)*DXBC + hh*HD + p;
    sXh[p*STR + s] = xbh[off];
    sXl[p*STR + s] = xbl[off];
  }
  __syncthreads();
  int lane = tid & 63, wid = tid >> 6;
  int wbase = wid*16;
  int fr = lane & 15, fk = (lane>>4)*8;
  int orow = (lane>>4)*4;
  int l = wbase + fr;
  float acs_l = sAcs[l];
  size_t cbase = (((size_t)(b*NCH + c)*NH) + hh)*8192;
  size_t sbase = ((size_t)(b*NCH + c))*16384;
  size_t crow  = (size_t)(t0+l)*DXBC + DI + DSTATE;

  f32x4 accU[4], accD[4];
  #pragma unroll
  for (int j=0;j<4;j++){
    accU[j] = (f32x4){0.f,0.f,0.f,0.f};
    accD[j] = (f32x4){0.f,0.f,0.f,0.f};
  }
  #pragma unroll
  for (int kk=0; kk<4; ++kk){
    int ko = kk*32 + fk;
    bf16x8 ch8 = *(const bf16x8*)(xbh + crow + ko);
    bf16x8 cl8 = *(const bf16x8*)(xbl + crow + ko);
    #pragma unroll
    for (int j=0;j<4;j++){
      int prow = j*16 + fr;
      bf16x8 ph = *(const bf16x8*)(cst_h + cbase + prow*128 + ko);
      bf16x8 pl = *(const bf16x8*)(cst_l + cbase + prow*128 + ko);
      accU[j] = MFMA(ch8, ph, accU[j]);
      accU[j] = MFMA(ch8, pl, accU[j]);
      accU[j] = MFMA(cl8, ph, accU[j]);
    }
  }
  #pragma unroll
  for (int kk=0; kk<4; ++kk){
    int sc = kk*32 + fk;
    const float* rp = Sraw + sbase + (size_t)l*128 + sc;
    bf16x8 ah, al;
    #pragma unroll
    for (int jj=0;jj<8;jj++){
      int s = sc + jj;
      float v = (s <= l) ? rp[jj]*__expf(acs_l - sAcs[s])*sDt[s] : 0.f;
      us h2 = f2b(v);
      ((us*)&ah)[jj] = h2;
      ((us*)&al)[jj] = f2b(v - b2f(h2));
    }
    #pragma unroll
    for (int j=0;j<4;j++){
      bf16x8 xh = *(const bf16x8*)(sXh + (j*16+fr)*STR + sc);
      bf16x8 xl = *(const bf16x8*)(sXl + (j*16+fr)*STR + sc);
      accD[j] = MFMA(ah, xh, accD[j]);
      accD[j] = MFMA(ah, xl, accD[j]);
      accD[j] = MFMA(al, xh, accD[j]);
    }
  }
  #pragma unroll
  for (int r=0;r<4;r++){
    int lo = wbase + orow + r;
    float ea = __expf(sAcs[lo]);
    #pragma unroll
    for (int j=0;j<4;j++)
      Yf[(size_t)(t0+lo)*DI + hh*HD + j*16 + fr] = accD[j][r] + ea*accU[j][r];
  }
}

// ---------------- gate + RMSNorm (vectorized, 384 thr): ab = rms((Y + x*Dp)*silu(z))*nw --------
__global__ __launch_bounds__(384) void k_gatenorm(const float* __restrict__ Yf,
                           const us* __restrict__ xbh, const us* __restrict__ xbl,
                           const float* __restrict__ zx, const float* __restrict__ Dp_l,
                           const float* __restrict__ nw, us* __restrict__ yh, us* __restrict__ yl){
  __shared__ float red[6];
  __shared__ float stot;
  int row = blockIdx.x;
  int tid = threadIdx.x;
  int d = tid*8;                     // 360 active vec8 groups (tid<360)
  bool act = (d < DI);
  float yv_[8];
  float ss = 0.f;
  if (act){
    const float* yp = Yf + (size_t)row*DI + d;
    const float* zp = zx + (size_t)row*ZXS + d;
    bf16x8 xh8 = *(const bf16x8*)(xbh + (size_t)row*DXBC + d);
    bf16x8 xl8 = *(const bf16x8*)(xbl + (size_t)row*DXBC + d);
    float dp = Dp_l[d >> 6];
    #pragma unroll
    for (int j=0;j<8;j++){
      float xv = b2f(((us*)&xh8)[j]) + b2f(((us*)&xl8)[j]);
      float yv = yp[j] + xv * dp;
      float zv = zp[j];
      yv *= zv * sigmoidf_(zv);
      yv_[j] = yv;
      ss += yv*yv;
    }
  }
  #pragma unroll
  for (int off=32; off>0; off>>=1) ss += __shfl_down(ss, off, 64);
  int lane = tid & 63, wid = tid >> 6;
  if (lane == 0) red[wid] = ss;
  __syncthreads();
  if (tid == 0){
    float s = 0.f;
    #pragma unroll
    for (int i=0;i<6;i++) s += red[i];
    stot = s;
  }
  __syncthreads();
  float rs = rsqrtf(stot / (float)DI + 1e-5f);
  if (act){
    const float* nwp = nw + d;
    bf16x8 oh, ol;
    #pragma unroll
    for (int j=0;j<8;j++){
      float v = yv_[j] * rs * nwp[j];
      us hh = f2b(v);
      ((us*)&oh)[j] = hh;
      ((us*)&ol)[j] = f2b(v - b2f(hh));
    }
    *(bf16x8*)(yh + (size_t)row*DI + d) = oh;
    *(bf16x8*)(yl + (size_t)row*DI + d) = ol;
  }
}

// ---------------- final RMSNorm -> split bf16 pair ----------------
__global__ __launch_bounds__(256) void k_finalnorm(const float* __restrict__ h, const float* __restrict__ fnw,
                            us* __restrict__ oh, us* __restrict__ ol){
  __shared__ float red[4];
  __shared__ float stot;
  int row = blockIdx.x;
  int tid = threadIdx.x;
  float v_[6];
  float ss = 0.f;
  #pragma unroll
  for (int i=0;i<6;i++){
    int d = tid + i*256;
    if (d < DM){ v_[i] = h[(size_t)row*DM + d]; ss += v_[i]*v_[i]; }
    else v_[i] = 0.f;
  }
  #pragma unroll
  for (int off=32; off>0; off>>=1) ss += __shfl_down(ss, off, 64);
  int lane = tid & 63, wid = tid >> 6;
  if (lane == 0) red[wid] = ss;
  __syncthreads();
  if (tid == 0) stot = red[0]+red[1]+red[2]+red[3];
  __syncthreads();
  float rs = rsqrtf(stot / (float)DM + 1e-5f);
  #pragma unroll
  for (int i=0;i<6;i++){
    int d = tid + i*256;
    if (d < DM){
      float v = v_[i] * rs * fnw[d];
      split2(v, &oh[(size_t)row*DM + d], &ol[(size_t)row*DM + d]);
    }
  }
}

extern "C" void kernel_launch(void* const* d_in, const int* in_sizes, int n_in,
                              void* d_out, int out_size, void* d_ws, size_t ws_size,
                              hipStream_t stream){
  const int*   tok   = (const int*)d_in[0];
  const float* emb   = (const float*)d_in[1];
  const float* Win   = (const float*)d_in[2];
  const float* convw = (const float*)d_in[3];
  const float* convb = (const float*)d_in[4];
  const float* dtbias= (const float*)d_in[5];
  const float* Alog  = (const float*)d_in[6];
  const float* Dp    = (const float*)d_in[7];
  const float* normw = (const float*)d_in[8];
  const float* Wout  = (const float*)d_in[9];
  const float* fnw   = (const float*)d_in[10];

  float* ws = (float*)d_ws;
  // layout (floats): 326.7 MB total (R14-proven)
  float* h    = ws;                        // 4096x1440 fp32
  float* zx   = ws + 5898240;              // 4096x6144 fp32
  us*    xbh  = (us*)(ws + 31064064);      // 4096x3136 bf16 hi
  us*    xbl  = (us*)(ws + 37486592);      // 4096x3136 bf16 lo
  us*    hp_h = (us*)(ws + 31064064);      // h pair overlay (dead once conv writes xb)
  us*    hp_l = (us*)(ws + 34013184);
  float* dtb  = ws + 43909120;
  float* acs  = ws + 44093440;
  float* Yf   = ws + 44277760;             // 4096x2880 fp32
  us* cst_h   = (us*)(ws + 56074240);      // OVERLAID with ab pair (disjoint lifetimes)
  us* cst_l   = (us*)(ws + 61972480);
  us* ab_h    = (us*)(ws + 56074240);
  us* ab_l    = (us*)(ws + 61972480);
  float* Sraw = ws + 67870720;             // 32x128x128 fp32
  us* winh    = (us*)(ws + 68395008);      // Win pair [6144][1440]
  us* winl    = (us*)(ws + 72818688);
  us* wouth   = (us*)(ws + 77242368);      // Wout pair [1536][2880] (also emb pair for logits)
  us* woutl   = (us*)(ws + 79454208);

  k_embed<<<(ROWS*DM+255)/256, 256, 0, stream>>>(tok, emb, h);
  k_split_rows<<<2880, 256, 0, stream>>>(h, hp_h, hp_l, DM);
  k_transcast_sp<<<dim3(ZXS/64, DM/32), 256, 0, stream>>>(Win, winh, winl, DM, DPROJ);  // layer 0
  for (int lyr=0; lyr<NLAYERS; ++lyr){
    // GEMM1 (1536 blocks) + fused Wout[lyr] transcast tail (2160 blocks)
    k_gemm_sp<false,false><<<1536 + 2160, 256, 0, stream>>>(
        hp_h, hp_l, winh, winl, zx, DM, ZXS, ZXS, ZXS/128, nullptr, nullptr,
        1536, Wout + (size_t)lyr*DI*DM, wouth, woutl, DI, DM, 24);
    k_conv2<<<dim3(13, 128, BB), 256, 0, stream>>>(
        zx, convw + (size_t)lyr*DXBC*4, convb + (size_t)lyr*DXBC, xbh, xbl,
        dtbias + lyr*NH, dtb);
    k_sraw<<<dim3(NCH, BB), 256, 0, stream>>>(xbh, xbl, Sraw);
    k_ssd_state_sp<<<dim3(NH, NCH, BB), 256, 0, stream>>>(xbh, xbl, dtb, Alog + lyr*NH, acs, cst_h, cst_l);
    k_ssd_scan2<<<dim3(NH, BB, 8), 256, 0, stream>>>(acs, cst_h, cst_l);
    k_ssd_y_sp<<<dim3(NH, NCH, BB), 512, 0, stream>>>(xbh, xbl, dtb, acs, cst_h, cst_l, Sraw, Yf);
    k_gatenorm<<<ROWS, 384, 0, stream>>>(Yf, xbh, xbl, zx, Dp + lyr*NH, normw + (size_t)lyr*DI, ab_h, ab_l);
    // GEMM2 (384 blocks) + fused Win[lyr+1] transcast tail (4320 blocks, except last layer)
    if (lyr+1 < NLAYERS){
      k_gemm_sp<true,true><<<384 + 4320, 256, 0, stream>>>(
          ab_h, ab_l, wouth, woutl, h, DI, DM, DM, 1536/128, hp_h, hp_l,
          384, Win + (size_t)(lyr+1)*DM*DPROJ, winh, winl, DM, DPROJ, 96);
    } else {
      k_gemm_sp<true,true><<<384, 256, 0, stream>>>(
          ab_h, ab_l, wouth, woutl, h, DI, DM, DM, 1536/128, hp_h, hp_l,
          384, nullptr, nullptr, nullptr, 0, 0, 1);
    }
  }
  k_finalnorm<<<ROWS, 256, 0, stream>>>(h, fnw, ab_h, ab_l);
  k_split_rows<<<180, 256, 0, stream>>>(emb, wouth, woutl, DM);   // emb pair -> wout region
  k_gemm_sp<false,false><<<(VOCABSZ/128)*(ROWS/128), 256, 0, stream>>>(
      ab_h, ab_l, wouth, woutl, (float*)d_out, DM, VOCABSZ, VOCABSZ, VOCABSZ/128, nullptr, nullptr,
      (VOCABSZ/128)*(ROWS/128), nullptr, nullptr, nullptr, 0, 0, 1);
}